// Round 1
// baseline (2374.511 us; speedup 1.0000x reference)
//
#include <hip/hip_runtime.h>
#include <math.h>

// GCN: out = Ahat @ (relu(Ahat @ X @ W1 + b1)) @ W2 + b2
// Ahat = D^-1/2 (A + I) D^-1/2, deg counts incoming dst edges + self loop.
//
// Layer 1 computed as (Ahat X) W1  (scatter over 128 feats instead of 256)
// Layer 2 computed as Ahat (H1 W2) (scatter over 128 feats instead of 256)

constexpr int NN = 50000;
constexpr int NE = 640000;
constexpr int F_IN = 128;
constexpr int F_HID = 256;
constexpr int F_OUT = 128;

__global__ void k_init_deg(int* __restrict__ deg) {
    int v = blockIdx.x * blockDim.x + threadIdx.x;
    if (v < NN) deg[v] = 1;  // self loop
}

__global__ void k_count_deg(const int* __restrict__ dst, int* __restrict__ deg) {
    int e = blockIdx.x * blockDim.x + threadIdx.x;
    if (e < NE) atomicAdd(&deg[dst[e]], 1);
}

__global__ void k_dinv(const int* __restrict__ deg, float* __restrict__ dinv) {
    int v = blockIdx.x * blockDim.x + threadIdx.x;
    if (v < NN) dinv[v] = rsqrtf((float)deg[v]);  // deg >= 1 always
}

// out[v][:] = dinv[v]^2 * feat[v][:] (+ bias)   -- the self-loop term; plain
// stores, so it also initializes the poisoned output buffer.
template <int F, bool BIAS>
__global__ void k_agg_init(const float* __restrict__ feat,
                           const float* __restrict__ bias,
                           const float* __restrict__ dinv,
                           float* __restrict__ out) {
    constexpr int CPV = F / 4;  // float4 chunks per node row
    int gid = blockIdx.x * blockDim.x + threadIdx.x;
    int v = gid / CPV;
    int c = gid % CPV;
    if (v >= NN) return;
    float di = dinv[v];
    float s = di * di;
    float4 x = reinterpret_cast<const float4*>(feat)[(size_t)v * CPV + c];
    float4 o;
    if (BIAS) {
        float4 b = reinterpret_cast<const float4*>(bias)[c];
        o.x = s * x.x + b.x; o.y = s * x.y + b.y;
        o.z = s * x.z + b.z; o.w = s * x.w + b.w;
    } else {
        o.x = s * x.x; o.y = s * x.y; o.z = s * x.z; o.w = s * x.w;
    }
    reinterpret_cast<float4*>(out)[(size_t)v * CPV + c] = o;
}

// out[dst[e]][:] += dinv[src]*dinv[dst] * feat[src[e]][:]
template <int F>
__global__ void k_agg_edges(const float* __restrict__ feat,
                            const int* __restrict__ src,
                            const int* __restrict__ dst,
                            const float* __restrict__ dinv,
                            float* __restrict__ out) {
    constexpr int CPE = F / 4;  // 32 float4 chunks per edge
    int gid = blockIdx.x * blockDim.x + threadIdx.x;
    int e = gid / CPE;
    int c = gid % CPE;
    if (e >= NE) return;
    int s = src[e];
    int d = dst[e];
    float nrm = dinv[s] * dinv[d];
    float4 x = reinterpret_cast<const float4*>(feat)[(size_t)s * CPE + c];
    float* o = out + (size_t)d * F + c * 4;
    atomicAdd(o + 0, nrm * x.x);
    atomicAdd(o + 1, nrm * x.y);
    atomicAdd(o + 2, nrm * x.z);
    atomicAdd(o + 3, nrm * x.w);
}

// out[M,N] = X[M,K] @ W[K,N] (+bias) (relu).  One thread per output column,
// TM rows staged in LDS per block (rows contiguous -> tile load is one
// contiguous chunk). LDS reads are wave-uniform broadcasts (conflict-free);
// W reads are coalesced across threads.
template <int K, int N, int TM, bool RELU, bool BIAS>
__global__ __launch_bounds__(N) void k_gemm(const float* __restrict__ X,
                                            const float* __restrict__ W,
                                            const float* __restrict__ bias,
                                            float* __restrict__ out) {
    __shared__ float xs[TM * K];
    const int n = threadIdx.x;
    const int row0 = blockIdx.x * TM;

    const float4* src4 = reinterpret_cast<const float4*>(X + (size_t)row0 * K);
    float4* xs4 = reinterpret_cast<float4*>(xs);
    constexpr int TILE4 = TM * K / 4;
    for (int i = n; i < TILE4; i += N) xs4[i] = src4[i];
    __syncthreads();

    float acc[TM];
#pragma unroll
    for (int r = 0; r < TM; ++r) acc[r] = 0.f;

    for (int k4 = 0; k4 < K / 4; ++k4) {
        float w0 = W[(size_t)(4 * k4 + 0) * N + n];
        float w1 = W[(size_t)(4 * k4 + 1) * N + n];
        float w2 = W[(size_t)(4 * k4 + 2) * N + n];
        float w3 = W[(size_t)(4 * k4 + 3) * N + n];
#pragma unroll
        for (int r = 0; r < TM; ++r) {
            float4 xv = xs4[r * (K / 4) + k4];
            acc[r] += xv.x * w0 + xv.y * w1 + xv.z * w2 + xv.w * w3;
        }
    }

    float b = BIAS ? bias[n] : 0.f;
#pragma unroll
    for (int r = 0; r < TM; ++r) {
        float v = acc[r] + b;
        if (RELU) v = fmaxf(v, 0.f);
        out[(size_t)(row0 + r) * N + n] = v;
    }
}

extern "C" void kernel_launch(void* const* d_in, const int* in_sizes, int n_in,
                              void* d_out, int out_size, void* d_ws, size_t ws_size,
                              hipStream_t stream) {
    const float* x  = (const float*)d_in[0];
    const int*   ei = (const int*)d_in[1];
    const float* W1 = (const float*)d_in[2];
    const float* b1 = (const float*)d_in[3];
    const float* W2 = (const float*)d_in[4];
    const float* b2 = (const float*)d_in[5];
    float* out = (float*)d_out;

    const int* src = ei;        // edge_index[0]
    const int* dst = ei + NE;   // edge_index[1]

    // workspace layout (all 256B-aligned):
    char* ws = (char*)d_ws;
    int*   deg  = (int*)ws;                                   // 200 KB
    float* dinv = (float*)(ws + 262144);                      // 200 KB
    float* H1   = (float*)(ws + 524288);                      // 50000*256*4 = 51.2 MB
    float* H2   = (float*)(ws + 524288 + 51200000);           // 50000*128*4 = 25.6 MB
    // total ~77.3 MB

    constexpr int BT = 256;
    const int gN  = (NN + BT - 1) / BT;           // 196
    const int gE  = (NE + BT - 1) / BT;           // 2500
    const int gA  = (NN * (F_IN / 4) + BT - 1) / BT;   // 6250
    const int gAE = (NE * (F_IN / 4) + BT - 1) / BT;   // 80000
    const int gM  = NN / 16;                      // 3125 (exact)

    // degrees + dinv
    k_init_deg<<<gN, BT, 0, stream>>>(deg);
    k_count_deg<<<gE, BT, 0, stream>>>(dst, deg);
    k_dinv<<<gN, BT, 0, stream>>>(deg, dinv);

    // layer 1: agg1 = Ahat @ x   (agg1 lives in d_out as scratch)
    k_agg_init<F_IN, false><<<gA, BT, 0, stream>>>(x, nullptr, dinv, out);
    k_agg_edges<F_IN><<<gAE, BT, 0, stream>>>(x, src, dst, dinv, out);
    // H1 = relu(agg1 @ W1 + b1)
    k_gemm<F_IN, F_HID, 16, true, true><<<gM, F_HID, 0, stream>>>(out, W1, b1, H1);

    // layer 2: H2 = H1 @ W2
    k_gemm<F_HID, F_OUT, 16, false, false><<<gM, F_OUT, 0, stream>>>(H1, W2, nullptr, H2);
    // out = Ahat @ H2 + b2
    k_agg_init<F_OUT, true><<<gA, BT, 0, stream>>>(H2, b2, dinv, out);
    k_agg_edges<F_OUT><<<gAE, BT, 0, stream>>>(H2, src, dst, dinv, out);
}

// Round 2
// 427.159 us; speedup vs baseline: 5.5588x; 5.5588x over previous
//
#include <hip/hip_runtime.h>
#include <math.h>

// GCN: out = Ahat @ (relu(Ahat @ X @ W1 + b1)) @ W2 + b2
// Ahat = D^-1/2 (A + I) D^-1/2, deg counts incoming dst edges + self loop.
//
// R1: scatter-atomic aggregation replaced by dst-CSR + gather (no f32 atomics).
// Layer 1 computed as (Ahat X) W1  (aggregate over 128 feats, not 256)
// Layer 2 computed as Ahat (H1 W2) (aggregate over 128 feats, not 256)

constexpr int NN = 50000;
constexpr int NE = 640000;
constexpr int F_IN = 128;
constexpr int F_HID = 256;
constexpr int F_OUT = 128;

__global__ void k_zero_deg(int* __restrict__ deg) {
    int v = blockIdx.x * blockDim.x + threadIdx.x;
    if (v < NN) deg[v] = 0;  // edge-only degree; self loop added in dinv
}

__global__ void k_count_deg(const int* __restrict__ dst, int* __restrict__ deg) {
    int e = blockIdx.x * blockDim.x + threadIdx.x;
    if (e < NE) atomicAdd(&deg[dst[e]], 1);
}

__global__ void k_dinv(const int* __restrict__ deg, float* __restrict__ dinv) {
    int v = blockIdx.x * blockDim.x + threadIdx.x;
    if (v < NN) dinv[v] = rsqrtf((float)(deg[v] + 1));  // +1 = self loop
}

// Single-block exclusive scan of deg -> row_ptr; also zeroes cursor.
constexpr int SCAN_T = 1024;
__global__ __launch_bounds__(SCAN_T) void k_scan(const int* __restrict__ deg,
                                                 int* __restrict__ row_ptr,
                                                 int* __restrict__ cursor) {
    __shared__ int sm[SCAN_T];
    __shared__ int base_s;
    if (threadIdx.x == 0) base_s = 0;
    __syncthreads();
    const int nchunk = (NN + SCAN_T - 1) / SCAN_T;
    for (int ch = 0; ch < nchunk; ++ch) {
        int i = ch * SCAN_T + threadIdx.x;
        int v = (i < NN) ? deg[i] : 0;
        sm[threadIdx.x] = v;
        __syncthreads();
        for (int off = 1; off < SCAN_T; off <<= 1) {
            int t = (threadIdx.x >= off) ? sm[threadIdx.x - off] : 0;
            __syncthreads();
            sm[threadIdx.x] += t;
            __syncthreads();
        }
        if (i < NN) {
            row_ptr[i] = base_s + sm[threadIdx.x] - v;  // exclusive prefix
            cursor[i] = 0;
        }
        int total = sm[SCAN_T - 1];
        __syncthreads();
        if (threadIdx.x == 0) base_s += total;
        __syncthreads();
    }
    if (threadIdx.x == 0) row_ptr[NN] = base_s;  // == NE
}

__global__ void k_fill_csr(const int* __restrict__ src, const int* __restrict__ dst,
                           const int* __restrict__ row_ptr, int* __restrict__ cursor,
                           int* __restrict__ csr_src) {
    int e = blockIdx.x * blockDim.x + threadIdx.x;
    if (e >= NE) return;
    int d = dst[e];
    int slot = row_ptr[d] + atomicAdd(&cursor[d], 1);
    csr_src[slot] = src[e];
}

// out[v][:] = dinv[v]^2*feat[v][:] + sum_{e: dst=v} dinv[v]*dinv[src]*feat[src][:] (+bias)
// One node per 32-lane group (lane owns a float4 column); gathers are 512B
// coalesced rows; csr_src/dinv reads are group-uniform broadcasts.
template <int F, bool BIAS>
__global__ __launch_bounds__(256) void k_gather(const float* __restrict__ feat,
                                                const int* __restrict__ csr_src,
                                                const int* __restrict__ row_ptr,
                                                const float* __restrict__ dinv,
                                                const float* __restrict__ bias,
                                                float* __restrict__ out) {
    constexpr int C4 = F / 4;        // float4 chunks per row (32)
    constexpr int NPB = 256 / C4;    // nodes per block (8)
    int node = blockIdx.x * NPB + threadIdx.x / C4;
    int c = threadIdx.x % C4;
    if (node >= NN) return;
    float di = dinv[node];
    const float4* f4 = reinterpret_cast<const float4*>(feat);
    float4 self = f4[(size_t)node * C4 + c];
    float s2 = di * di;
    float4 acc = make_float4(s2 * self.x, s2 * self.y, s2 * self.z, s2 * self.w);
    int beg = row_ptr[node], end = row_ptr[node + 1];
    for (int j = beg; j < end; ++j) {
        int s = csr_src[j];
        float nrm = di * dinv[s];
        float4 v = f4[(size_t)s * C4 + c];
        acc.x += nrm * v.x; acc.y += nrm * v.y;
        acc.z += nrm * v.z; acc.w += nrm * v.w;
    }
    if (BIAS) {
        float4 b = reinterpret_cast<const float4*>(bias)[c];
        acc.x += b.x; acc.y += b.y; acc.z += b.z; acc.w += b.w;
    }
    reinterpret_cast<float4*>(out)[(size_t)node * C4 + c] = acc;
}

// out[M,N] = X[M,K] @ W[K,N] (+bias) (relu).  One thread per output column,
// TM rows staged in LDS per block. LDS reads are wave-uniform broadcasts;
// W reads are coalesced across threads.
template <int K, int N, int TM, bool RELU, bool BIAS>
__global__ __launch_bounds__(N) void k_gemm(const float* __restrict__ X,
                                            const float* __restrict__ W,
                                            const float* __restrict__ bias,
                                            float* __restrict__ out) {
    __shared__ float xs[TM * K];
    const int n = threadIdx.x;
    const int row0 = blockIdx.x * TM;

    const float4* src4 = reinterpret_cast<const float4*>(X + (size_t)row0 * K);
    float4* xs4 = reinterpret_cast<float4*>(xs);
    constexpr int TILE4 = TM * K / 4;
    for (int i = n; i < TILE4; i += N) xs4[i] = src4[i];
    __syncthreads();

    float acc[TM];
#pragma unroll
    for (int r = 0; r < TM; ++r) acc[r] = 0.f;

    for (int k4 = 0; k4 < K / 4; ++k4) {
        float w0 = W[(size_t)(4 * k4 + 0) * N + n];
        float w1 = W[(size_t)(4 * k4 + 1) * N + n];
        float w2 = W[(size_t)(4 * k4 + 2) * N + n];
        float w3 = W[(size_t)(4 * k4 + 3) * N + n];
#pragma unroll
        for (int r = 0; r < TM; ++r) {
            float4 xv = xs4[r * (K / 4) + k4];
            acc[r] += xv.x * w0 + xv.y * w1 + xv.z * w2 + xv.w * w3;
        }
    }

    float b = BIAS ? bias[n] : 0.f;
#pragma unroll
    for (int r = 0; r < TM; ++r) {
        float v = acc[r] + b;
        if (RELU) v = fmaxf(v, 0.f);
        out[(size_t)(row0 + r) * N + n] = v;
    }
}

extern "C" void kernel_launch(void* const* d_in, const int* in_sizes, int n_in,
                              void* d_out, int out_size, void* d_ws, size_t ws_size,
                              hipStream_t stream) {
    const float* x  = (const float*)d_in[0];
    const int*   ei = (const int*)d_in[1];
    const float* W1 = (const float*)d_in[2];
    const float* b1 = (const float*)d_in[3];
    const float* W2 = (const float*)d_in[4];
    const float* b2 = (const float*)d_in[5];
    float* out = (float*)d_out;

    const int* src = ei;        // edge_index[0]
    const int* dst = ei + NE;   // edge_index[1]

    // workspace layout (256B-aligned blocks):
    char* ws = (char*)d_ws;
    int*   deg     = (int*)ws;                         // 200 KB
    int*   cursor  = (int*)(ws + 262144);              // 200 KB
    int*   row_ptr = (int*)(ws + 524288);              // 200 KB (+4)
    float* dinv    = (float*)(ws + 786432);            // 200 KB
    int*   csr_src = (int*)(ws + 1048576);             // 2.56 MB
    float* H1      = (float*)(ws + 4194304);           // 51.2 MB
    float* H2      = (float*)(ws + 4194304 + 51200000);// 25.6 MB  (~81 MB total)

    constexpr int BT = 256;
    const int gN  = (NN + BT - 1) / BT;            // 196
    const int gE  = (NE + BT - 1) / BT;            // 2500
    const int gG  = (NN + 7) / 8;                  // 6250 (8 nodes/block)
    const int gM  = NN / 16;                       // 3125

    // CSR build
    k_zero_deg<<<gN, BT, 0, stream>>>(deg);
    k_count_deg<<<gE, BT, 0, stream>>>(dst, deg);
    k_dinv<<<gN, BT, 0, stream>>>(deg, dinv);
    k_scan<<<1, SCAN_T, 0, stream>>>(deg, row_ptr, cursor);
    k_fill_csr<<<gE, BT, 0, stream>>>(src, dst, row_ptr, cursor, csr_src);

    // layer 1: agg1 = Ahat @ x   (agg1 lives in d_out as scratch)
    k_gather<F_IN, false><<<gG, BT, 0, stream>>>(x, csr_src, row_ptr, dinv, nullptr, out);
    // H1 = relu(agg1 @ W1 + b1)
    k_gemm<F_IN, F_HID, 16, true, true><<<gM, F_HID, 0, stream>>>(out, W1, b1, H1);

    // layer 2: H2 = H1 @ W2
    k_gemm<F_HID, F_OUT, 16, false, false><<<gM, F_OUT, 0, stream>>>(H1, W2, nullptr, H2);
    // out = Ahat @ H2 + b2
    k_gather<F_OUT, true><<<gG, BT, 0, stream>>>(H2, csr_src, row_ptr, dinv, b2, out);
}

// Round 4
// 319.946 us; speedup vs baseline: 7.4216x; 1.3351x over previous
//
#include <hip/hip_runtime.h>
#include <math.h>

// GCN: out = Ahat @ (relu(Ahat @ X @ W1 + b1)) @ W2 + b2
// Ahat = D^-1/2 (A + I) D^-1/2.
//
// R1: dst-CSR + gather aggregation (no f32 atomics).
// R2: parallel 3-kernel scan; GEMM retiled 4cols x RPT rows per thread.
// R3: fix R2 GEMM bug -- col-thread count must be N/4 (was hardcoded 64,
//     which wrote OOB columns for the N=128 layer-2 GEMM).

constexpr int NN = 50000;
constexpr int NE = 640000;
constexpr int F_IN = 128;
constexpr int F_HID = 256;
constexpr int F_OUT = 128;

__global__ void k_zero_deg(int* __restrict__ deg) {
    int v = blockIdx.x * blockDim.x + threadIdx.x;
    if (v < NN) deg[v] = 0;  // edge-only degree; self loop added in dinv
}

__global__ void k_count_deg(const int* __restrict__ dst, int* __restrict__ deg) {
    int e = blockIdx.x * blockDim.x + threadIdx.x;
    if (e < NE) atomicAdd(&deg[dst[e]], 1);
}

__global__ void k_dinv(const int* __restrict__ deg, float* __restrict__ dinv) {
    int v = blockIdx.x * blockDim.x + threadIdx.x;
    if (v < NN) dinv[v] = rsqrtf((float)(deg[v] + 1));  // +1 = self loop
}

// ---- parallel exclusive scan of deg[NN] -> row_ptr ----
constexpr int SCB = 256;                       // scan chunk
constexpr int NCHUNK = (NN + SCB - 1) / SCB;   // 196

// per-chunk exclusive scan; chunk totals to blk_sum
__global__ __launch_bounds__(SCB) void k_scan_blk(const int* __restrict__ deg,
                                                  int* __restrict__ row_ptr,
                                                  int* __restrict__ blk_sum) {
    __shared__ int sm[SCB];
    int i = blockIdx.x * SCB + threadIdx.x;
    int v = (i < NN) ? deg[i] : 0;
    sm[threadIdx.x] = v;
    __syncthreads();
    for (int off = 1; off < SCB; off <<= 1) {
        int t = (threadIdx.x >= off) ? sm[threadIdx.x - off] : 0;
        __syncthreads();
        sm[threadIdx.x] += t;
        __syncthreads();
    }
    if (i < NN) row_ptr[i] = sm[threadIdx.x] - v;
    if (threadIdx.x == SCB - 1) blk_sum[blockIdx.x] = sm[SCB - 1];
}

// single small block: exclusive scan of the 196 chunk sums
__global__ __launch_bounds__(SCB) void k_scan_top(const int* __restrict__ blk_sum,
                                                  int* __restrict__ blk_off) {
    __shared__ int sm[SCB];
    int v = (threadIdx.x < NCHUNK) ? blk_sum[threadIdx.x] : 0;
    sm[threadIdx.x] = v;
    __syncthreads();
    for (int off = 1; off < SCB; off <<= 1) {
        int t = (threadIdx.x >= off) ? sm[threadIdx.x - off] : 0;
        __syncthreads();
        sm[threadIdx.x] += t;
        __syncthreads();
    }
    if (threadIdx.x < NCHUNK) blk_off[threadIdx.x] = sm[threadIdx.x] - v;
}

// add chunk offsets, zero cursors, finalize row_ptr[NN]
__global__ __launch_bounds__(SCB) void k_scan_add(int* __restrict__ row_ptr,
                                                  const int* __restrict__ blk_off,
                                                  int* __restrict__ cursor) {
    int i = blockIdx.x * SCB + threadIdx.x;
    if (i < NN) {
        row_ptr[i] += blk_off[blockIdx.x];
        cursor[i] = 0;
    }
    if (i == 0) row_ptr[NN] = NE;
}

__global__ void k_fill_csr(const int* __restrict__ src, const int* __restrict__ dst,
                           const int* __restrict__ row_ptr, int* __restrict__ cursor,
                           int* __restrict__ csr_src) {
    int e = blockIdx.x * blockDim.x + threadIdx.x;
    if (e >= NE) return;
    int d = dst[e];
    int slot = row_ptr[d] + atomicAdd(&cursor[d], 1);
    csr_src[slot] = src[e];
}

// out[v][:] = dinv[v]^2*feat[v][:] + sum_{e: dst=v} dinv[v]*dinv[src]*feat[src][:] (+bias)
template <int F, bool BIAS>
__global__ __launch_bounds__(256) void k_gather(const float* __restrict__ feat,
                                                const int* __restrict__ csr_src,
                                                const int* __restrict__ row_ptr,
                                                const float* __restrict__ dinv,
                                                const float* __restrict__ bias,
                                                float* __restrict__ out) {
    constexpr int C4 = F / 4;        // float4 chunks per row (32)
    constexpr int NPB = 256 / C4;    // nodes per block (8)
    int node = blockIdx.x * NPB + threadIdx.x / C4;
    int c = threadIdx.x % C4;
    if (node >= NN) return;
    float di = dinv[node];
    const float4* f4 = reinterpret_cast<const float4*>(feat);
    float4 self = f4[(size_t)node * C4 + c];
    float s2 = di * di;
    float4 acc = make_float4(s2 * self.x, s2 * self.y, s2 * self.z, s2 * self.w);
    int beg = row_ptr[node], end = row_ptr[node + 1];
    for (int j = beg; j < end; ++j) {
        int s = csr_src[j];
        float nrm = di * dinv[s];
        float4 v = f4[(size_t)s * C4 + c];
        acc.x += nrm * v.x; acc.y += nrm * v.y;
        acc.z += nrm * v.z; acc.w += nrm * v.w;
    }
    if (BIAS) {
        float4 b = reinterpret_cast<const float4*>(bias)[c];
        acc.x += b.x; acc.y += b.y; acc.z += b.z; acc.w += b.w;
    }
    reinterpret_cast<float4*>(out)[(size_t)node * C4 + c] = acc;
}

// out[M,N] = X[M,K] @ W[K,N] (+bias)(relu), W row-major [K][N].
// Block: TM=64 rows x all N cols, 256 threads.
//   CT = N/4 col-threads (each owns 4 contiguous cols, float4 W loads)
//   NRG = 256/CT row-groups, RPT = TM/NRG rows per thread.
// LDS x-tile reads are (half-)wave-uniform broadcasts (<=2 addrs/wave: free).
template <int K, int N, bool RELU, bool BIAS>
__global__ __launch_bounds__(256) void k_gemm(const float* __restrict__ X,
                                              const float* __restrict__ W,
                                              const float* __restrict__ bias,
                                              float* __restrict__ out, int M) {
    constexpr int TM = 64;        // rows per block
    constexpr int BK = 128;       // K tile
    constexpr int CT = N / 4;     // col-threads (64 for N=256, 32 for N=128)
    constexpr int NRG = 256 / CT; // row-groups (4 or 8)
    constexpr int RPT = TM / NRG; // rows per thread (16 or 8)
    static_assert(CT * NRG == 256 && NRG * RPT == TM, "tiling");
    __shared__ float xs[TM * BK]; // 32 KB
    float4* xs4 = reinterpret_cast<float4*>(xs);
    const int c  = threadIdx.x % CT;   // col-group: cols 4c..4c+3
    const int rg = threadIdx.x / CT;   // row-group
    const int row0 = blockIdx.x * TM;

    float acc[RPT][4];
#pragma unroll
    for (int r = 0; r < RPT; ++r)
        acc[r][0] = acc[r][1] = acc[r][2] = acc[r][3] = 0.f;

#pragma unroll
    for (int kt = 0; kt < K / BK; ++kt) {
        __syncthreads();  // protect previous tile (no-op first iter)
        const float* xsrc = X + (size_t)row0 * K + kt * BK;
        for (int i = threadIdx.x; i < TM * BK / 4; i += 256) {
            int r = i / (BK / 4), cc = i % (BK / 4);
            float4 v = (row0 + r < M)
                           ? reinterpret_cast<const float4*>(xsrc + (size_t)r * K)[cc]
                           : make_float4(0.f, 0.f, 0.f, 0.f);
            xs4[i] = v;
        }
        __syncthreads();

        for (int k4 = 0; k4 < BK / 4; ++k4) {
            const int kbase = kt * BK + 4 * k4;
            float4 w0 = reinterpret_cast<const float4*>(W + (size_t)(kbase + 0) * N)[c];
            float4 w1 = reinterpret_cast<const float4*>(W + (size_t)(kbase + 1) * N)[c];
            float4 w2 = reinterpret_cast<const float4*>(W + (size_t)(kbase + 2) * N)[c];
            float4 w3 = reinterpret_cast<const float4*>(W + (size_t)(kbase + 3) * N)[c];
#pragma unroll
            for (int r = 0; r < RPT; ++r) {
                float4 xv = xs4[(rg * RPT + r) * (BK / 4) + k4];
                acc[r][0] += xv.x * w0.x + xv.y * w1.x + xv.z * w2.x + xv.w * w3.x;
                acc[r][1] += xv.x * w0.y + xv.y * w1.y + xv.z * w2.y + xv.w * w3.y;
                acc[r][2] += xv.x * w0.z + xv.y * w1.z + xv.z * w2.z + xv.w * w3.z;
                acc[r][3] += xv.x * w0.w + xv.y * w1.w + xv.z * w2.w + xv.w * w3.w;
            }
        }
    }

    float4 b = BIAS ? reinterpret_cast<const float4*>(bias)[c]
                    : make_float4(0.f, 0.f, 0.f, 0.f);
#pragma unroll
    for (int r = 0; r < RPT; ++r) {
        int row = row0 + rg * RPT + r;
        if (row < M) {
            float4 o;
            o.x = acc[r][0] + b.x; o.y = acc[r][1] + b.y;
            o.z = acc[r][2] + b.z; o.w = acc[r][3] + b.w;
            if (RELU) {
                o.x = fmaxf(o.x, 0.f); o.y = fmaxf(o.y, 0.f);
                o.z = fmaxf(o.z, 0.f); o.w = fmaxf(o.w, 0.f);
            }
            reinterpret_cast<float4*>(out + (size_t)row * N)[c] = o;
        }
    }
}

extern "C" void kernel_launch(void* const* d_in, const int* in_sizes, int n_in,
                              void* d_out, int out_size, void* d_ws, size_t ws_size,
                              hipStream_t stream) {
    const float* x  = (const float*)d_in[0];
    const int*   ei = (const int*)d_in[1];
    const float* W1 = (const float*)d_in[2];
    const float* b1 = (const float*)d_in[3];
    const float* W2 = (const float*)d_in[4];
    const float* b2 = (const float*)d_in[5];
    float* out = (float*)d_out;

    const int* src = ei;        // edge_index[0]
    const int* dst = ei + NE;   // edge_index[1]

    // workspace layout (256B-aligned blocks):
    char* ws = (char*)d_ws;
    int*   deg     = (int*)ws;                           // 200 KB
    int*   cursor  = (int*)(ws + 262144);                // 200 KB
    int*   row_ptr = (int*)(ws + 524288);                // 200 KB (+4)
    float* dinv    = (float*)(ws + 786432);              // 200 KB
    int*   csr_src = (int*)(ws + 1048576);               // 2.56 MB
    int*   blk_sum = (int*)(ws + 3670016);               // 784 B
    int*   blk_off = (int*)(ws + 3674112);               // 784 B
    float* H1      = (float*)(ws + 4194304);             // 51.2 MB
    float* H2      = (float*)(ws + 4194304 + 51200000);  // 25.6 MB

    constexpr int BT = 256;
    const int gN  = (NN + BT - 1) / BT;            // 196
    const int gE  = (NE + BT - 1) / BT;            // 2500
    const int gG  = (NN + 7) / 8;                  // 6250 (8 nodes/block)
    const int gM  = (NN + 63) / 64;                // 782 (64 rows/block)

    // CSR build
    k_zero_deg<<<gN, BT, 0, stream>>>(deg);
    k_count_deg<<<gE, BT, 0, stream>>>(dst, deg);
    k_dinv<<<gN, BT, 0, stream>>>(deg, dinv);
    k_scan_blk<<<NCHUNK, SCB, 0, stream>>>(deg, row_ptr, blk_sum);
    k_scan_top<<<1, SCB, 0, stream>>>(blk_sum, blk_off);
    k_scan_add<<<NCHUNK, SCB, 0, stream>>>(row_ptr, blk_off, cursor);
    k_fill_csr<<<gE, BT, 0, stream>>>(src, dst, row_ptr, cursor, csr_src);

    // layer 1: agg1 = Ahat @ x   (agg1 lives in d_out as scratch)
    k_gather<F_IN, false><<<gG, BT, 0, stream>>>(x, csr_src, row_ptr, dinv, nullptr, out);
    // H1 = relu(agg1 @ W1 + b1)
    k_gemm<F_IN, F_HID, true, true><<<gM, BT, 0, stream>>>(out, W1, b1, H1, NN);

    // layer 2: H2 = H1 @ W2
    k_gemm<F_HID, F_OUT, false, false><<<gM, BT, 0, stream>>>(H1, W2, nullptr, H2, NN);
    // out = Ahat @ H2 + b2
    k_gather<F_OUT, true><<<gG, BT, 0, stream>>>(H2, csr_src, row_ptr, dinv, b2, out);
}

// Round 5
// 271.456 us; speedup vs baseline: 8.7473x; 1.1786x over previous
//
#include <hip/hip_runtime.h>
#include <math.h>

// GCN: out = Ahat @ (relu(Ahat @ X @ W1 + b1)) @ W2 + b2
// R1: dst-CSR + gather aggregation (no f32 atomics).
// R2/R3: parallel scan; f32 GEMM retile.
// R4: GEMMs moved to MFMA with split-bf16 (hi+lo) 3-pass for f32-grade
//     accuracy: A@W ~= Ahi@Whi + Ahi@Wlo + Alo@Whi. LDS-free, barrier-free:
//     waves own 16-row strips, A-frags from global, W pre-packed per-lane.

constexpr int NN = 50000;
constexpr int NE = 640000;
constexpr int NPAD = 50048;          // rows padded to 64
constexpr int F_IN = 128;
constexpr int F_HID = 256;
constexpr int F_OUT = 128;

typedef __attribute__((ext_vector_type(8))) short bf16x8;   // 8 bf16 = 4 VGPRs
typedef __attribute__((ext_vector_type(4))) float f32x4;
typedef __attribute__((ext_vector_type(8))) unsigned short u16x8;

__device__ inline unsigned short f2bf(float v) {  // RNE f32->bf16
    unsigned int u = __float_as_uint(v);
    return (unsigned short)((u + 0x7fff + ((u >> 16) & 1)) >> 16);
}
__device__ inline float bf2f(unsigned short h) {
    return __uint_as_float(((unsigned int)h) << 16);
}

__global__ void k_zero_deg(int* __restrict__ deg) {
    int v = blockIdx.x * blockDim.x + threadIdx.x;
    if (v < NN) deg[v] = 0;
}

__global__ void k_count_deg(const int* __restrict__ dst, int* __restrict__ deg) {
    int e = blockIdx.x * blockDim.x + threadIdx.x;
    if (e < NE) atomicAdd(&deg[dst[e]], 1);
}

__global__ void k_dinv(const int* __restrict__ deg, float* __restrict__ dinv) {
    int v = blockIdx.x * blockDim.x + threadIdx.x;
    if (v < NN) dinv[v] = rsqrtf((float)(deg[v] + 1));  // +1 self loop
}

// ---- parallel exclusive scan of deg[NN] -> row_ptr ----
constexpr int SCB = 256;
constexpr int NCHUNK = (NN + SCB - 1) / SCB;  // 196

__global__ __launch_bounds__(SCB) void k_scan_blk(const int* __restrict__ deg,
                                                  int* __restrict__ row_ptr,
                                                  int* __restrict__ blk_sum) {
    __shared__ int sm[SCB];
    int i = blockIdx.x * SCB + threadIdx.x;
    int v = (i < NN) ? deg[i] : 0;
    sm[threadIdx.x] = v;
    __syncthreads();
    for (int off = 1; off < SCB; off <<= 1) {
        int t = (threadIdx.x >= off) ? sm[threadIdx.x - off] : 0;
        __syncthreads();
        sm[threadIdx.x] += t;
        __syncthreads();
    }
    if (i < NN) row_ptr[i] = sm[threadIdx.x] - v;
    if (threadIdx.x == SCB - 1) blk_sum[blockIdx.x] = sm[SCB - 1];
}

__global__ __launch_bounds__(SCB) void k_scan_top(const int* __restrict__ blk_sum,
                                                  int* __restrict__ blk_off) {
    __shared__ int sm[SCB];
    int v = (threadIdx.x < NCHUNK) ? blk_sum[threadIdx.x] : 0;
    sm[threadIdx.x] = v;
    __syncthreads();
    for (int off = 1; off < SCB; off <<= 1) {
        int t = (threadIdx.x >= off) ? sm[threadIdx.x - off] : 0;
        __syncthreads();
        sm[threadIdx.x] += t;
        __syncthreads();
    }
    if (threadIdx.x < NCHUNK) blk_off[threadIdx.x] = sm[threadIdx.x] - v;
}

__global__ __launch_bounds__(SCB) void k_scan_add(int* __restrict__ row_ptr,
                                                  const int* __restrict__ blk_off,
                                                  int* __restrict__ cursor) {
    int i = blockIdx.x * SCB + threadIdx.x;
    if (i < NN) {
        row_ptr[i] += blk_off[blockIdx.x];
        cursor[i] = 0;
    }
    if (i == 0) row_ptr[NN] = NE;
}

__global__ void k_fill_csr(const int* __restrict__ src, const int* __restrict__ dst,
                           const int* __restrict__ row_ptr, int* __restrict__ cursor,
                           int* __restrict__ csr_src) {
    int e = blockIdx.x * blockDim.x + threadIdx.x;
    if (e >= NE) return;
    int d = dst[e];
    int slot = row_ptr[d] + atomicAdd(&cursor[d], 1);
    csr_src[slot] = src[e];
}

// Pack W[K][N] f32 -> fragment-native bf16 hi/lo: idx = ((kt*NT+nt)*64+lane)*8+e
// lane = kg*16 + col16; element e -> W[kt*32 + kg*8 + e][nt*16 + col16]
template <int K, int N>
__global__ __launch_bounds__(256) void k_wpack(const float* __restrict__ W,
                                               unsigned short* __restrict__ hi,
                                               unsigned short* __restrict__ lo) {
    constexpr int NT = N / 16, KT = K / 32;
    int t = blockIdx.x * 256 + threadIdx.x;
    if (t >= KT * NT * 64) return;
    int lane = t & 63, nt = (t >> 6) % NT, kt = (t >> 6) / NT;
    int col = nt * 16 + (lane & 15), kg = lane >> 4;
    unsigned short hb[8], lb[8];
#pragma unroll
    for (int e = 0; e < 8; ++e) {
        int k = kt * 32 + kg * 8 + e;
        float v = W[(size_t)k * N + col];
        unsigned short h = f2bf(v);
        hb[e] = h;
        lb[e] = f2bf(v - bf2f(h));
    }
    *reinterpret_cast<u16x8*>(hi + (size_t)t * 8) = *reinterpret_cast<u16x8*>(hb);
    *reinterpret_cast<u16x8*>(lo + (size_t)t * 8) = *reinterpret_cast<u16x8*>(lb);
}

// Aggregation: out[v] = dinv[v]^2*feat[v] + sum dinv[v]*dinv[s]*feat[s] (+bias)
// SPLITOUT: write hi/lo bf16 arrays; else f32.
template <int F, bool BIAS, bool SPLITOUT>
__global__ __launch_bounds__(256) void k_gather(const float* __restrict__ feat,
                                                const int* __restrict__ csr_src,
                                                const int* __restrict__ row_ptr,
                                                const float* __restrict__ dinv,
                                                const float* __restrict__ bias,
                                                float* __restrict__ out_f,
                                                unsigned short* __restrict__ out_hi,
                                                unsigned short* __restrict__ out_lo) {
    constexpr int C4 = F / 4;
    constexpr int NPB = 256 / C4;  // 8 nodes/block
    int node = blockIdx.x * NPB + threadIdx.x / C4;
    int c = threadIdx.x % C4;
    if (node >= NN) return;
    float di = dinv[node];
    const float4* f4 = reinterpret_cast<const float4*>(feat);
    float4 self = f4[(size_t)node * C4 + c];
    float s2 = di * di;
    float4 acc = make_float4(s2 * self.x, s2 * self.y, s2 * self.z, s2 * self.w);
    int beg = row_ptr[node], end = row_ptr[node + 1];
    for (int j = beg; j < end; ++j) {
        int s = csr_src[j];
        float nrm = di * dinv[s];
        float4 v = f4[(size_t)s * C4 + c];
        acc.x += nrm * v.x; acc.y += nrm * v.y;
        acc.z += nrm * v.z; acc.w += nrm * v.w;
    }
    if (BIAS) {
        float4 b = reinterpret_cast<const float4*>(bias)[c];
        acc.x += b.x; acc.y += b.y; acc.z += b.z; acc.w += b.w;
    }
    if (SPLITOUT) {
        ushort4 hh, ll;
        hh.x = f2bf(acc.x); ll.x = f2bf(acc.x - bf2f(hh.x));
        hh.y = f2bf(acc.y); ll.y = f2bf(acc.y - bf2f(hh.y));
        hh.z = f2bf(acc.z); ll.z = f2bf(acc.z - bf2f(hh.z));
        hh.w = f2bf(acc.w); ll.w = f2bf(acc.w - bf2f(hh.w));
        *reinterpret_cast<ushort4*>(out_hi + (size_t)node * F + c * 4) = hh;
        *reinterpret_cast<ushort4*>(out_lo + (size_t)node * F + c * 4) = ll;
    } else {
        reinterpret_cast<float4*>(out_f)[(size_t)node * C4 + c] = acc;
    }
}

// C[M,N] = A[M,K] @ W[K,N] via 3-pass split-bf16 MFMA 16x16x32.
// Block = 256 thr = 4 waves; wave owns 16-row strip x all N.
// A-frag: lane reads A[row0 + lane%16][kt*32 + (lane/16)*8 .. +8) (16B global).
// B-frag: packed idx ((kt*NT+nt)*64+lane)*8 (coalesced 1KB/wave, L2-hot).
template <int K, int N, bool RELU, bool BIAS, bool SPLITOUT>
__global__ __launch_bounds__(256) void k_gemm_mfma(
    const unsigned short* __restrict__ Ahi, const unsigned short* __restrict__ Alo,
    const unsigned short* __restrict__ Bhi, const unsigned short* __restrict__ Blo,
    const float* __restrict__ bias,
    unsigned short* __restrict__ Chi, unsigned short* __restrict__ Clo,
    float* __restrict__ Cf) {
    constexpr int NT = N / 16, KT = K / 32;
    const int lane = threadIdx.x & 63;
    const int wave = threadIdx.x >> 6;
    const int row0 = blockIdx.x * 64 + wave * 16;
    const int arow = row0 + (lane & 15);
    const int kg = lane >> 4;

    f32x4 acc[NT];
#pragma unroll
    for (int nt = 0; nt < NT; ++nt) acc[nt] = (f32x4){0.f, 0.f, 0.f, 0.f};

    const unsigned short* pa_hi = Ahi + (size_t)arow * K + kg * 8;
    const unsigned short* pa_lo = Alo + (size_t)arow * K + kg * 8;
    const unsigned short* pb_hi = Bhi + (size_t)lane * 8;
    const unsigned short* pb_lo = Blo + (size_t)lane * 8;

#pragma unroll
    for (int kt = 0; kt < KT; ++kt) {
        bf16x8 ah = *reinterpret_cast<const bf16x8*>(pa_hi + kt * 32);
        bf16x8 al = *reinterpret_cast<const bf16x8*>(pa_lo + kt * 32);
#pragma unroll
        for (int nt = 0; nt < NT; ++nt) {
            bf16x8 bh = *reinterpret_cast<const bf16x8*>(pb_hi + (size_t)(kt * NT + nt) * 512);
            bf16x8 bl = *reinterpret_cast<const bf16x8*>(pb_lo + (size_t)(kt * NT + nt) * 512);
            acc[nt] = __builtin_amdgcn_mfma_f32_16x16x32_bf16(ah, bh, acc[nt], 0, 0, 0);
            acc[nt] = __builtin_amdgcn_mfma_f32_16x16x32_bf16(ah, bl, acc[nt], 0, 0, 0);
            acc[nt] = __builtin_amdgcn_mfma_f32_16x16x32_bf16(al, bh, acc[nt], 0, 0, 0);
        }
    }

    // C/D layout: col = lane&15, row = (lane>>4)*4 + i   [m89/m91 verified]
    const int crow0 = row0 + (lane >> 4) * 4;
    const int ccol = lane & 15;
#pragma unroll
    for (int nt = 0; nt < NT; ++nt) {
        int col = nt * 16 + ccol;
        float bv = BIAS ? bias[col] : 0.f;
#pragma unroll
        for (int i = 0; i < 4; ++i) {
            float v = acc[nt][i] + bv;
            if (RELU) v = fmaxf(v, 0.f);
            size_t idx = (size_t)(crow0 + i) * N + col;
            if (SPLITOUT) {
                unsigned short h = f2bf(v);
                Chi[idx] = h;
                Clo[idx] = f2bf(v - bf2f(h));
            } else {
                Cf[idx] = v;
            }
        }
    }
}

extern "C" void kernel_launch(void* const* d_in, const int* in_sizes, int n_in,
                              void* d_out, int out_size, void* d_ws, size_t ws_size,
                              hipStream_t stream) {
    const float* x  = (const float*)d_in[0];
    const int*   ei = (const int*)d_in[1];
    const float* W1 = (const float*)d_in[2];
    const float* b1 = (const float*)d_in[3];
    const float* W2 = (const float*)d_in[4];
    const float* b2 = (const float*)d_in[5];
    float* out = (float*)d_out;

    const int* src = ei;
    const int* dst = ei + NE;

    // workspace layout (all offsets 256-aligned):
    char* ws = (char*)d_ws;
    int*   deg     = (int*)ws;                               // 200 KB
    int*   cursor  = (int*)(ws + 262144);
    int*   row_ptr = (int*)(ws + 524288);
    float* dinv    = (float*)(ws + 786432);
    int*   csr_src = (int*)(ws + 1048576);                   // 2.56 MB
    int*   blk_sum = (int*)(ws + 3670016);
    int*   blk_off = (int*)(ws + 3674112);
    unsigned short* W1hi = (unsigned short*)(ws + 3678208);  // 64 KB each
    unsigned short* W1lo = (unsigned short*)(ws + 3743744);
    unsigned short* W2hi = (unsigned short*)(ws + 3809280);
    unsigned short* W2lo = (unsigned short*)(ws + 3874816);
    unsigned short* A1hi = (unsigned short*)(ws + 4194304);  // NPAD*128*2 = 12.81 MB
    unsigned short* A1lo = (unsigned short*)(ws + 17006592); // 12.81 MB
    unsigned short* H1hi = (unsigned short*)(ws + 29818880); // NPAD*256*2 = 25.62 MB
    unsigned short* H1lo = (unsigned short*)(ws + 55443456); // 25.62 MB
    float* H2 = (float*)(ws + 4194304);  // aliases A1hi+A1lo (dead by then), 25.62 MB
    // total ws usage ~81 MB

    constexpr int BT = 256;
    const int gN = (NN + BT - 1) / BT;   // 196
    const int gE = (NE + BT - 1) / BT;   // 2500
    const int gG = (NN + 7) / 8;         // 6250
    const int gMM = NPAD / 64;           // 782

    // CSR build
    k_zero_deg<<<gN, BT, 0, stream>>>(deg);
    k_count_deg<<<gE, BT, 0, stream>>>(dst, deg);
    k_dinv<<<gN, BT, 0, stream>>>(deg, dinv);
    k_scan_blk<<<NCHUNK, SCB, 0, stream>>>(deg, row_ptr, blk_sum);
    k_scan_top<<<1, SCB, 0, stream>>>(blk_sum, blk_off);
    k_scan_add<<<NCHUNK, SCB, 0, stream>>>(row_ptr, blk_off, cursor);
    k_fill_csr<<<gE, BT, 0, stream>>>(src, dst, row_ptr, cursor, csr_src);

    // W packs (tiny)
    k_wpack<F_IN, F_HID><<<16, BT, 0, stream>>>(W1, W1hi, W1lo);
    k_wpack<F_HID, F_OUT><<<16, BT, 0, stream>>>(W2, W2hi, W2lo);

    // layer 1: agg1 = Ahat @ x  (split bf16 out)
    k_gather<F_IN, false, true><<<gG, BT, 0, stream>>>(x, csr_src, row_ptr, dinv,
                                                       nullptr, nullptr, A1hi, A1lo);
    // H1 = relu(agg1 @ W1 + b1)  (split bf16 out)
    k_gemm_mfma<F_IN, F_HID, true, true, true><<<gMM, BT, 0, stream>>>(
        A1hi, A1lo, W1hi, W1lo, b1, H1hi, H1lo, nullptr);
    // H2 = H1 @ W2  (f32 out; H2 aliases dead A1)
    k_gemm_mfma<F_HID, F_OUT, false, false, false><<<gMM, BT, 0, stream>>>(
        H1hi, H1lo, W2hi, W2lo, nullptr, nullptr, nullptr, H2);
    // out = Ahat @ H2 + b2
    k_gather<F_OUT, true, false><<<gG, BT, 0, stream>>>(H2, csr_src, row_ptr, dinv,
                                                        b2, out, nullptr, nullptr);
}

// Round 6
// 259.797 us; speedup vs baseline: 9.1399x; 1.0449x over previous
//
#include <hip/hip_runtime.h>
#include <math.h>

// GCN: out = Ahat @ (relu(Ahat @ X @ W1 + b1)) @ W2 + b2
// R1: dst-CSR + gather aggregation (no f32 atomics).
// R2/R3: parallel scan; f32 GEMM retile.
// R4: split-bf16 (hi+lo) 3-pass MFMA GEMM: A@W ~= Ahi@Whi + Ahi@Wlo + Alo@Whi.
// R5: GEMM waves fattened to 64 rows x 128 cols (was 16 x all-N): 96 MFMAs per
//     24 loads per K-tile (was 48 per 34) -- R4 was latency-bound (MfmaUtil 6%,
//     VALUBusy 7%, HBM 3%) on the per-wave re-read of all of W from L2.

constexpr int NN = 50000;
constexpr int NE = 640000;
constexpr int NPAD = 50048;          // rows padded to 64
constexpr int F_IN = 128;
constexpr int F_HID = 256;
constexpr int F_OUT = 128;

typedef __attribute__((ext_vector_type(8))) short bf16x8;   // 8 bf16 = 4 VGPRs
typedef __attribute__((ext_vector_type(4))) float f32x4;
typedef __attribute__((ext_vector_type(8))) unsigned short u16x8;

__device__ inline unsigned short f2bf(float v) {  // RNE f32->bf16
    unsigned int u = __float_as_uint(v);
    return (unsigned short)((u + 0x7fff + ((u >> 16) & 1)) >> 16);
}
__device__ inline float bf2f(unsigned short h) {
    return __uint_as_float(((unsigned int)h) << 16);
}

__global__ void k_zero_deg(int* __restrict__ deg) {
    int v = blockIdx.x * blockDim.x + threadIdx.x;
    if (v < NN) deg[v] = 0;
}

__global__ void k_count_deg(const int* __restrict__ dst, int* __restrict__ deg) {
    int e = blockIdx.x * blockDim.x + threadIdx.x;
    if (e < NE) atomicAdd(&deg[dst[e]], 1);
}

__global__ void k_dinv(const int* __restrict__ deg, float* __restrict__ dinv) {
    int v = blockIdx.x * blockDim.x + threadIdx.x;
    if (v < NN) dinv[v] = rsqrtf((float)(deg[v] + 1));  // +1 self loop
}

// ---- parallel exclusive scan of deg[NN] -> row_ptr ----
constexpr int SCB = 256;
constexpr int NCHUNK = (NN + SCB - 1) / SCB;  // 196

__global__ __launch_bounds__(SCB) void k_scan_blk(const int* __restrict__ deg,
                                                  int* __restrict__ row_ptr,
                                                  int* __restrict__ blk_sum) {
    __shared__ int sm[SCB];
    int i = blockIdx.x * SCB + threadIdx.x;
    int v = (i < NN) ? deg[i] : 0;
    sm[threadIdx.x] = v;
    __syncthreads();
    for (int off = 1; off < SCB; off <<= 1) {
        int t = (threadIdx.x >= off) ? sm[threadIdx.x - off] : 0;
        __syncthreads();
        sm[threadIdx.x] += t;
        __syncthreads();
    }
    if (i < NN) row_ptr[i] = sm[threadIdx.x] - v;
    if (threadIdx.x == SCB - 1) blk_sum[blockIdx.x] = sm[SCB - 1];
}

__global__ __launch_bounds__(SCB) void k_scan_top(const int* __restrict__ blk_sum,
                                                  int* __restrict__ blk_off) {
    __shared__ int sm[SCB];
    int v = (threadIdx.x < NCHUNK) ? blk_sum[threadIdx.x] : 0;
    sm[threadIdx.x] = v;
    __syncthreads();
    for (int off = 1; off < SCB; off <<= 1) {
        int t = (threadIdx.x >= off) ? sm[threadIdx.x - off] : 0;
        __syncthreads();
        sm[threadIdx.x] += t;
        __syncthreads();
    }
    if (threadIdx.x < NCHUNK) blk_off[threadIdx.x] = sm[threadIdx.x] - v;
}

__global__ __launch_bounds__(SCB) void k_scan_add(int* __restrict__ row_ptr,
                                                  const int* __restrict__ blk_off,
                                                  int* __restrict__ cursor) {
    int i = blockIdx.x * SCB + threadIdx.x;
    if (i < NN) {
        row_ptr[i] += blk_off[blockIdx.x];
        cursor[i] = 0;
    }
    if (i == 0) row_ptr[NN] = NE;
}

__global__ void k_fill_csr(const int* __restrict__ src, const int* __restrict__ dst,
                           const int* __restrict__ row_ptr, int* __restrict__ cursor,
                           int* __restrict__ csr_src) {
    int e = blockIdx.x * blockDim.x + threadIdx.x;
    if (e >= NE) return;
    int d = dst[e];
    int slot = row_ptr[d] + atomicAdd(&cursor[d], 1);
    csr_src[slot] = src[e];
}

// Pack W[K][N] f32 -> fragment-native bf16 hi/lo: idx = ((kt*NT+nt)*64+lane)*8+e
// lane = kg*16 + col16; element e -> W[kt*32 + kg*8 + e][nt*16 + col16]
template <int K, int N>
__global__ __launch_bounds__(256) void k_wpack(const float* __restrict__ W,
                                               unsigned short* __restrict__ hi,
                                               unsigned short* __restrict__ lo) {
    constexpr int NT = N / 16, KT = K / 32;
    int t = blockIdx.x * 256 + threadIdx.x;
    if (t >= KT * NT * 64) return;
    int lane = t & 63, nt = (t >> 6) % NT, kt = (t >> 6) / NT;
    int col = nt * 16 + (lane & 15), kg = lane >> 4;
    unsigned short hb[8], lb[8];
#pragma unroll
    for (int e = 0; e < 8; ++e) {
        int k = kt * 32 + kg * 8 + e;
        float v = W[(size_t)k * N + col];
        unsigned short h = f2bf(v);
        hb[e] = h;
        lb[e] = f2bf(v - bf2f(h));
    }
    *reinterpret_cast<u16x8*>(hi + (size_t)t * 8) = *reinterpret_cast<u16x8*>(hb);
    *reinterpret_cast<u16x8*>(lo + (size_t)t * 8) = *reinterpret_cast<u16x8*>(lb);
}

// Aggregation: out[v] = dinv[v]^2*feat[v] + sum dinv[v]*dinv[s]*feat[s] (+bias)
// SPLITOUT: write hi/lo bf16 arrays; else f32.
template <int F, bool BIAS, bool SPLITOUT>
__global__ __launch_bounds__(256) void k_gather(const float* __restrict__ feat,
                                                const int* __restrict__ csr_src,
                                                const int* __restrict__ row_ptr,
                                                const float* __restrict__ dinv,
                                                const float* __restrict__ bias,
                                                float* __restrict__ out_f,
                                                unsigned short* __restrict__ out_hi,
                                                unsigned short* __restrict__ out_lo) {
    constexpr int C4 = F / 4;
    constexpr int NPB = 256 / C4;  // 8 nodes/block
    int node = blockIdx.x * NPB + threadIdx.x / C4;
    int c = threadIdx.x % C4;
    if (node >= NN) return;
    float di = dinv[node];
    const float4* f4 = reinterpret_cast<const float4*>(feat);
    float4 self = f4[(size_t)node * C4 + c];
    float s2 = di * di;
    float4 acc = make_float4(s2 * self.x, s2 * self.y, s2 * self.z, s2 * self.w);
    int beg = row_ptr[node], end = row_ptr[node + 1];
    for (int j = beg; j < end; ++j) {
        int s = csr_src[j];
        float nrm = di * dinv[s];
        float4 v = f4[(size_t)s * C4 + c];
        acc.x += nrm * v.x; acc.y += nrm * v.y;
        acc.z += nrm * v.z; acc.w += nrm * v.w;
    }
    if (BIAS) {
        float4 b = reinterpret_cast<const float4*>(bias)[c];
        acc.x += b.x; acc.y += b.y; acc.z += b.z; acc.w += b.w;
    }
    if (SPLITOUT) {
        ushort4 hh, ll;
        hh.x = f2bf(acc.x); ll.x = f2bf(acc.x - bf2f(hh.x));
        hh.y = f2bf(acc.y); ll.y = f2bf(acc.y - bf2f(hh.y));
        hh.z = f2bf(acc.z); ll.z = f2bf(acc.z - bf2f(hh.z));
        hh.w = f2bf(acc.w); ll.w = f2bf(acc.w - bf2f(hh.w));
        *reinterpret_cast<ushort4*>(out_hi + (size_t)node * F + c * 4) = hh;
        *reinterpret_cast<ushort4*>(out_lo + (size_t)node * F + c * 4) = ll;
    } else {
        reinterpret_cast<float4*>(out_f)[(size_t)node * C4 + c] = acc;
    }
}

// C[M,N] = A[M,K] @ W[K,N] via 3-pass split-bf16 MFMA 16x16x32.
// One wave per block (64 thr); wave owns 64 rows x 128 cols:
// WR=4 row-tiles x WC=8 col-tiles, acc[4][8] (128 VGPRs).
// Per K-tile: 8 A-loads + 16 B-loads feed 96 MFMAs (4:1), deep ILP across acc.
// A-frag: lane reads A[rt-row + lane%16][kt*32 + (lane/16)*8 ..+8) (16B).
// B-frag: packed ((kt*NTall+nt)*64+lane)*8 (coalesced 1KB/wave, L2-hot).
template <int K, int N, bool RELU, bool BIAS, bool SPLITOUT>
__global__ __launch_bounds__(64) void k_gemm_mfma(
    const unsigned short* __restrict__ Ahi, const unsigned short* __restrict__ Alo,
    const unsigned short* __restrict__ Bhi, const unsigned short* __restrict__ Blo,
    const float* __restrict__ bias,
    unsigned short* __restrict__ Chi, unsigned short* __restrict__ Clo,
    float* __restrict__ Cf) {
    constexpr int NTall = N / 16, KT = K / 32;
    constexpr int WR = 4;                 // 16-row tiles per wave (64 rows)
    constexpr int WC = 8;                 // 16-col tiles per wave (128 cols)
    constexpr int NRB = NPAD / 64;        // 782 row-blocks
    const int lane = threadIdx.x;
    const int rb = blockIdx.x % NRB;
    const int cb = blockIdx.x / NRB;
    const int row0 = rb * 64;
    const int ct0 = cb * WC;
    const int r16 = lane & 15;
    const int kg = lane >> 4;

    f32x4 acc[WR][WC];
#pragma unroll
    for (int rt = 0; rt < WR; ++rt)
#pragma unroll
        for (int ct = 0; ct < WC; ++ct) acc[rt][ct] = (f32x4){0.f, 0.f, 0.f, 0.f};

    const unsigned short* pa_hi = Ahi + (size_t)(row0 + r16) * K + kg * 8;
    const unsigned short* pa_lo = Alo + (size_t)(row0 + r16) * K + kg * 8;
    const unsigned short* pb_hi = Bhi + (size_t)lane * 8;
    const unsigned short* pb_lo = Blo + (size_t)lane * 8;

#pragma unroll
    for (int kt = 0; kt < KT; ++kt) {
        bf16x8 ah[WR], al[WR];
#pragma unroll
        for (int rt = 0; rt < WR; ++rt) {
            ah[rt] = *reinterpret_cast<const bf16x8*>(pa_hi + (size_t)rt * 16 * K + kt * 32);
            al[rt] = *reinterpret_cast<const bf16x8*>(pa_lo + (size_t)rt * 16 * K + kt * 32);
        }
#pragma unroll
        for (int ct = 0; ct < WC; ++ct) {
            const int nt = ct0 + ct;
            bf16x8 bh = *reinterpret_cast<const bf16x8*>(pb_hi + (size_t)(kt * NTall + nt) * 512);
            bf16x8 bl = *reinterpret_cast<const bf16x8*>(pb_lo + (size_t)(kt * NTall + nt) * 512);
#pragma unroll
            for (int rt = 0; rt < WR; ++rt) {
                acc[rt][ct] = __builtin_amdgcn_mfma_f32_16x16x32_bf16(ah[rt], bh, acc[rt][ct], 0, 0, 0);
                acc[rt][ct] = __builtin_amdgcn_mfma_f32_16x16x32_bf16(ah[rt], bl, acc[rt][ct], 0, 0, 0);
                acc[rt][ct] = __builtin_amdgcn_mfma_f32_16x16x32_bf16(al[rt], bh, acc[rt][ct], 0, 0, 0);
            }
        }
    }

    // C/D layout: col = lane&15, row = (lane>>4)*4 + i   [empirically verified R4]
    const int ccol = lane & 15;
#pragma unroll
    for (int rt = 0; rt < WR; ++rt) {
        const int crow0 = row0 + rt * 16 + (lane >> 4) * 4;
#pragma unroll
        for (int ct = 0; ct < WC; ++ct) {
            int col = (ct0 + ct) * 16 + ccol;
            float bv = BIAS ? bias[col] : 0.f;
#pragma unroll
            for (int i = 0; i < 4; ++i) {
                float v = acc[rt][ct][i] + bv;
                if (RELU) v = fmaxf(v, 0.f);
                size_t idx = (size_t)(crow0 + i) * N + col;
                if (SPLITOUT) {
                    unsigned short h = f2bf(v);
                    Chi[idx] = h;
                    Clo[idx] = f2bf(v - bf2f(h));
                } else {
                    Cf[idx] = v;
                }
            }
        }
    }
}

extern "C" void kernel_launch(void* const* d_in, const int* in_sizes, int n_in,
                              void* d_out, int out_size, void* d_ws, size_t ws_size,
                              hipStream_t stream) {
    const float* x  = (const float*)d_in[0];
    const int*   ei = (const int*)d_in[1];
    const float* W1 = (const float*)d_in[2];
    const float* b1 = (const float*)d_in[3];
    const float* W2 = (const float*)d_in[4];
    const float* b2 = (const float*)d_in[5];
    float* out = (float*)d_out;

    const int* src = ei;
    const int* dst = ei + NE;

    // workspace layout (all offsets 256-aligned):
    char* ws = (char*)d_ws;
    int*   deg     = (int*)ws;                               // 200 KB
    int*   cursor  = (int*)(ws + 262144);
    int*   row_ptr = (int*)(ws + 524288);
    float* dinv    = (float*)(ws + 786432);
    int*   csr_src = (int*)(ws + 1048576);                   // 2.56 MB
    int*   blk_sum = (int*)(ws + 3670016);
    int*   blk_off = (int*)(ws + 3674112);
    unsigned short* W1hi = (unsigned short*)(ws + 3678208);  // 64 KB each
    unsigned short* W1lo = (unsigned short*)(ws + 3743744);
    unsigned short* W2hi = (unsigned short*)(ws + 3809280);
    unsigned short* W2lo = (unsigned short*)(ws + 3874816);
    unsigned short* A1hi = (unsigned short*)(ws + 4194304);  // NPAD*128*2 = 12.81 MB
    unsigned short* A1lo = (unsigned short*)(ws + 17006592); // 12.81 MB
    unsigned short* H1hi = (unsigned short*)(ws + 29818880); // NPAD*256*2 = 25.62 MB
    unsigned short* H1lo = (unsigned short*)(ws + 55443456); // 25.62 MB
    float* H2 = (float*)(ws + 4194304);  // aliases A1hi+A1lo (dead by then), 25.62 MB
    // total ws usage ~81 MB

    constexpr int BT = 256;
    const int gN = (NN + BT - 1) / BT;   // 196
    const int gE = (NE + BT - 1) / BT;   // 2500
    const int gG = (NN + 7) / 8;         // 6250
    constexpr int NRB = NPAD / 64;       // 782

    // CSR build
    k_zero_deg<<<gN, BT, 0, stream>>>(deg);
    k_count_deg<<<gE, BT, 0, stream>>>(dst, deg);
    k_dinv<<<gN, BT, 0, stream>>>(deg, dinv);
    k_scan_blk<<<NCHUNK, SCB, 0, stream>>>(deg, row_ptr, blk_sum);
    k_scan_top<<<1, SCB, 0, stream>>>(blk_sum, blk_off);
    k_scan_add<<<NCHUNK, SCB, 0, stream>>>(row_ptr, blk_off, cursor);
    k_fill_csr<<<gE, BT, 0, stream>>>(src, dst, row_ptr, cursor, csr_src);

    // W packs (tiny)
    k_wpack<F_IN, F_HID><<<16, BT, 0, stream>>>(W1, W1hi, W1lo);
    k_wpack<F_HID, F_OUT><<<16, BT, 0, stream>>>(W2, W2hi, W2lo);

    // layer 1: agg1 = Ahat @ x  (split bf16 out)
    k_gather<F_IN, false, true><<<gG, BT, 0, stream>>>(x, csr_src, row_ptr, dinv,
                                                       nullptr, nullptr, A1hi, A1lo);
    // H1 = relu(agg1 @ W1 + b1)  (split bf16 out); grid = 782 row-blks x 2 col-blks
    k_gemm_mfma<F_IN, F_HID, true, true, true><<<NRB * 2, 64, 0, stream>>>(
        A1hi, A1lo, W1hi, W1lo, b1, H1hi, H1lo, nullptr);
    // H2 = H1 @ W2  (f32 out; H2 aliases dead A1); grid = 782 x 1
    k_gemm_mfma<F_HID, F_OUT, false, false, false><<<NRB, 64, 0, stream>>>(
        H1hi, H1lo, W2hi, W2lo, nullptr, nullptr, nullptr, H2);
    // out = Ahat @ H2 + b2
    k_gather<F_OUT, true, false><<<gG, BT, 0, stream>>>(H2, csr_src, row_ptr, dinv,
                                                        b2, out, nullptr, nullptr);
}

// Round 7
// 250.539 us; speedup vs baseline: 9.4776x; 1.0370x over previous
//
#include <hip/hip_runtime.h>
#include <math.h>

// GCN: out = Ahat @ (relu(Ahat @ X @ W1 + b1)) @ W2 + b2
// R1: dst-CSR + gather aggregation (no f32 atomics).
// R2/R3: parallel scan; f32 GEMM retile.
// R4: split-bf16 (hi+lo) 3-pass MFMA GEMM: A@W ~= Ahi@Whi + Ahi@Wlo + Alo@Whi.
// R5: GEMM waves fattened to 64 rows x 128 cols (latency fix, MfmaUtil 6%).
// R6: gather MLP -- 16 lanes/node (4 node-loops/wave), edge loop unrolled x4
//     (up to 32 rows in flight/wave, was ~4); GEMM-2 epilogue pre-scales H2 by
//     dinv so gather-2 is pure adds (no per-edge dinv load).

constexpr int NN = 50000;
constexpr int NE = 640000;
constexpr int NPAD = 50048;          // rows padded to 64
constexpr int F_IN = 128;
constexpr int F_HID = 256;
constexpr int F_OUT = 128;

typedef __attribute__((ext_vector_type(8))) short bf16x8;   // 8 bf16 = 4 VGPRs
typedef __attribute__((ext_vector_type(4))) float f32x4;
typedef __attribute__((ext_vector_type(8))) unsigned short u16x8;

__device__ inline unsigned short f2bf(float v) {  // RNE f32->bf16
    unsigned int u = __float_as_uint(v);
    return (unsigned short)((u + 0x7fff + ((u >> 16) & 1)) >> 16);
}
__device__ inline float bf2f(unsigned short h) {
    return __uint_as_float(((unsigned int)h) << 16);
}

__global__ void k_zero_deg(int* __restrict__ deg) {
    int v = blockIdx.x * blockDim.x + threadIdx.x;
    if (v < NN) deg[v] = 0;
}

__global__ void k_count_deg(const int* __restrict__ dst, int* __restrict__ deg) {
    int e = blockIdx.x * blockDim.x + threadIdx.x;
    if (e < NE) atomicAdd(&deg[dst[e]], 1);
}

__global__ void k_dinv(const int* __restrict__ deg, float* __restrict__ dinv) {
    int v = blockIdx.x * blockDim.x + threadIdx.x;
    if (v < NN) dinv[v] = rsqrtf((float)(deg[v] + 1));  // +1 self loop
}

// ---- parallel exclusive scan of deg[NN] -> row_ptr ----
constexpr int SCB = 256;
constexpr int NCHUNK = (NN + SCB - 1) / SCB;  // 196

__global__ __launch_bounds__(SCB) void k_scan_blk(const int* __restrict__ deg,
                                                  int* __restrict__ row_ptr,
                                                  int* __restrict__ blk_sum) {
    __shared__ int sm[SCB];
    int i = blockIdx.x * SCB + threadIdx.x;
    int v = (i < NN) ? deg[i] : 0;
    sm[threadIdx.x] = v;
    __syncthreads();
    for (int off = 1; off < SCB; off <<= 1) {
        int t = (threadIdx.x >= off) ? sm[threadIdx.x - off] : 0;
        __syncthreads();
        sm[threadIdx.x] += t;
        __syncthreads();
    }
    if (i < NN) row_ptr[i] = sm[threadIdx.x] - v;
    if (threadIdx.x == SCB - 1) blk_sum[blockIdx.x] = sm[SCB - 1];
}

__global__ __launch_bounds__(SCB) void k_scan_top(const int* __restrict__ blk_sum,
                                                  int* __restrict__ blk_off) {
    __shared__ int sm[SCB];
    int v = (threadIdx.x < NCHUNK) ? blk_sum[threadIdx.x] : 0;
    sm[threadIdx.x] = v;
    __syncthreads();
    for (int off = 1; off < SCB; off <<= 1) {
        int t = (threadIdx.x >= off) ? sm[threadIdx.x - off] : 0;
        __syncthreads();
        sm[threadIdx.x] += t;
        __syncthreads();
    }
    if (threadIdx.x < NCHUNK) blk_off[threadIdx.x] = sm[threadIdx.x] - v;
}

__global__ __launch_bounds__(SCB) void k_scan_add(int* __restrict__ row_ptr,
                                                  const int* __restrict__ blk_off,
                                                  int* __restrict__ cursor) {
    int i = blockIdx.x * SCB + threadIdx.x;
    if (i < NN) {
        row_ptr[i] += blk_off[blockIdx.x];
        cursor[i] = 0;
    }
    if (i == 0) row_ptr[NN] = NE;
}

__global__ void k_fill_csr(const int* __restrict__ src, const int* __restrict__ dst,
                           const int* __restrict__ row_ptr, int* __restrict__ cursor,
                           int* __restrict__ csr_src) {
    int e = blockIdx.x * blockDim.x + threadIdx.x;
    if (e >= NE) return;
    int d = dst[e];
    int slot = row_ptr[d] + atomicAdd(&cursor[d], 1);
    csr_src[slot] = src[e];
}

// Pack W[K][N] f32 -> fragment-native bf16 hi/lo: idx = ((kt*NT+nt)*64+lane)*8+e
template <int K, int N>
__global__ __launch_bounds__(256) void k_wpack(const float* __restrict__ W,
                                               unsigned short* __restrict__ hi,
                                               unsigned short* __restrict__ lo) {
    constexpr int NT = N / 16, KT = K / 32;
    int t = blockIdx.x * 256 + threadIdx.x;
    if (t >= KT * NT * 64) return;
    int lane = t & 63, nt = (t >> 6) % NT, kt = (t >> 6) / NT;
    int col = nt * 16 + (lane & 15), kg = lane >> 4;
    unsigned short hb[8], lb[8];
#pragma unroll
    for (int e = 0; e < 8; ++e) {
        int k = kt * 32 + kg * 8 + e;
        float v = W[(size_t)k * N + col];
        unsigned short h = f2bf(v);
        hb[e] = h;
        lb[e] = f2bf(v - bf2f(h));
    }
    *reinterpret_cast<u16x8*>(hi + (size_t)t * 8) = *reinterpret_cast<u16x8*>(hb);
    *reinterpret_cast<u16x8*>(lo + (size_t)t * 8) = *reinterpret_cast<u16x8*>(lb);
}

// Aggregation over F=128 features.
// PRESCALED=false: acc = dinv[v]*feat[v] + sum dinv[s]*feat[s];  out = dinv[v]*acc (+b)
// PRESCALED=true:  feat rows already carry dinv; acc = feat[v] + sum feat[s]; same epilogue.
// 16 lanes/node (lane owns float4 chunks c and c+16); 4 node-loops per wave;
// edge loop unrolled x4 => up to 32 independent row-loads in flight per wave.
template <bool BIAS, bool SPLITOUT, bool PRESCALED>
__global__ __launch_bounds__(256) void k_gather(const float* __restrict__ feat,
                                                const int* __restrict__ csr_src,
                                                const int* __restrict__ row_ptr,
                                                const float* __restrict__ dinv,
                                                const float* __restrict__ bias,
                                                float* __restrict__ out_f,
                                                unsigned short* __restrict__ out_hi,
                                                unsigned short* __restrict__ out_lo) {
    constexpr int C4 = 32;   // float4 chunks per 128-f row
    int node = blockIdx.x * 16 + (threadIdx.x >> 4);  // 16 nodes/block
    int c = threadIdx.x & 15;
    if (node >= NN) return;
    float di = dinv[node];
    const float4* f4 = reinterpret_cast<const float4*>(feat);
    const size_t self = (size_t)node * C4;
    float4 a0 = f4[self + c];
    float4 a1 = f4[self + c + 16];
    if (!PRESCALED) {
        a0.x *= di; a0.y *= di; a0.z *= di; a0.w *= di;
        a1.x *= di; a1.y *= di; a1.z *= di; a1.w *= di;
    }
    int j = row_ptr[node], end = row_ptr[node + 1];
    for (; j + 3 < end; j += 4) {
        int s0 = csr_src[j], s1 = csr_src[j + 1], s2 = csr_src[j + 2], s3 = csr_src[j + 3];
        float4 r0a = f4[(size_t)s0 * C4 + c],      r0b = f4[(size_t)s0 * C4 + c + 16];
        float4 r1a = f4[(size_t)s1 * C4 + c],      r1b = f4[(size_t)s1 * C4 + c + 16];
        float4 r2a = f4[(size_t)s2 * C4 + c],      r2b = f4[(size_t)s2 * C4 + c + 16];
        float4 r3a = f4[(size_t)s3 * C4 + c],      r3b = f4[(size_t)s3 * C4 + c + 16];
        if (PRESCALED) {
            a0.x += r0a.x + r1a.x + r2a.x + r3a.x;  a0.y += r0a.y + r1a.y + r2a.y + r3a.y;
            a0.z += r0a.z + r1a.z + r2a.z + r3a.z;  a0.w += r0a.w + r1a.w + r2a.w + r3a.w;
            a1.x += r0b.x + r1b.x + r2b.x + r3b.x;  a1.y += r0b.y + r1b.y + r2b.y + r3b.y;
            a1.z += r0b.z + r1b.z + r2b.z + r3b.z;  a1.w += r0b.w + r1b.w + r2b.w + r3b.w;
        } else {
            float n0 = dinv[s0], n1 = dinv[s1], n2 = dinv[s2], n3 = dinv[s3];
            a0.x += n0 * r0a.x + n1 * r1a.x + n2 * r2a.x + n3 * r3a.x;
            a0.y += n0 * r0a.y + n1 * r1a.y + n2 * r2a.y + n3 * r3a.y;
            a0.z += n0 * r0a.z + n1 * r1a.z + n2 * r2a.z + n3 * r3a.z;
            a0.w += n0 * r0a.w + n1 * r1a.w + n2 * r2a.w + n3 * r3a.w;
            a1.x += n0 * r0b.x + n1 * r1b.x + n2 * r2b.x + n3 * r3b.x;
            a1.y += n0 * r0b.y + n1 * r1b.y + n2 * r2b.y + n3 * r3b.y;
            a1.z += n0 * r0b.z + n1 * r1b.z + n2 * r2b.z + n3 * r3b.z;
            a1.w += n0 * r0b.w + n1 * r1b.w + n2 * r2b.w + n3 * r3b.w;
        }
    }
    for (; j < end; ++j) {
        int s = csr_src[j];
        float4 ra = f4[(size_t)s * C4 + c], rb = f4[(size_t)s * C4 + c + 16];
        float n = PRESCALED ? 1.f : dinv[s];
        a0.x += n * ra.x; a0.y += n * ra.y; a0.z += n * ra.z; a0.w += n * ra.w;
        a1.x += n * rb.x; a1.y += n * rb.y; a1.z += n * rb.z; a1.w += n * rb.w;
    }
    // epilogue: multiply by dinv[v], add bias
    a0.x *= di; a0.y *= di; a0.z *= di; a0.w *= di;
    a1.x *= di; a1.y *= di; a1.z *= di; a1.w *= di;
    if (BIAS) {
        float4 b0 = reinterpret_cast<const float4*>(bias)[c];
        float4 b1 = reinterpret_cast<const float4*>(bias)[c + 16];
        a0.x += b0.x; a0.y += b0.y; a0.z += b0.z; a0.w += b0.w;
        a1.x += b1.x; a1.y += b1.y; a1.z += b1.z; a1.w += b1.w;
    }
    if (SPLITOUT) {
        ushort4 hh, ll;
        hh.x = f2bf(a0.x); ll.x = f2bf(a0.x - bf2f(hh.x));
        hh.y = f2bf(a0.y); ll.y = f2bf(a0.y - bf2f(hh.y));
        hh.z = f2bf(a0.z); ll.z = f2bf(a0.z - bf2f(hh.z));
        hh.w = f2bf(a0.w); ll.w = f2bf(a0.w - bf2f(hh.w));
        *reinterpret_cast<ushort4*>(out_hi + (size_t)node * 128 + c * 4) = hh;
        *reinterpret_cast<ushort4*>(out_lo + (size_t)node * 128 + c * 4) = ll;
        hh.x = f2bf(a1.x); ll.x = f2bf(a1.x - bf2f(hh.x));
        hh.y = f2bf(a1.y); ll.y = f2bf(a1.y - bf2f(hh.y));
        hh.z = f2bf(a1.z); ll.z = f2bf(a1.z - bf2f(hh.z));
        hh.w = f2bf(a1.w); ll.w = f2bf(a1.w - bf2f(hh.w));
        *reinterpret_cast<ushort4*>(out_hi + (size_t)node * 128 + (c + 16) * 4) = hh;
        *reinterpret_cast<ushort4*>(out_lo + (size_t)node * 128 + (c + 16) * 4) = ll;
    } else {
        float4* o4 = reinterpret_cast<float4*>(out_f);
        o4[(size_t)node * C4 + c] = a0;
        o4[(size_t)node * C4 + c + 16] = a1;
    }
}

// C[M,N] = A[M,K] @ W[K,N] via 3-pass split-bf16 MFMA 16x16x32.
// One wave per block; wave owns 64 rows x 128 cols (acc[4][8]).
// PRESCALE: multiply output row r by dscale[r] (folds dinv into H2 for gather-2).
template <int K, int N, bool RELU, bool BIAS, bool SPLITOUT, bool PRESCALE>
__global__ __launch_bounds__(64) void k_gemm_mfma(
    const unsigned short* __restrict__ Ahi, const unsigned short* __restrict__ Alo,
    const unsigned short* __restrict__ Bhi, const unsigned short* __restrict__ Blo,
    const float* __restrict__ bias, const float* __restrict__ dscale,
    unsigned short* __restrict__ Chi, unsigned short* __restrict__ Clo,
    float* __restrict__ Cf) {
    constexpr int NTall = N / 16, KT = K / 32;
    constexpr int WR = 4;
    constexpr int WC = 8;
    constexpr int NRB = NPAD / 64;
    const int lane = threadIdx.x;
    const int rb = blockIdx.x % NRB;
    const int cb = blockIdx.x / NRB;
    const int row0 = rb * 64;
    const int ct0 = cb * WC;
    const int r16 = lane & 15;
    const int kg = lane >> 4;

    f32x4 acc[WR][WC];
#pragma unroll
    for (int rt = 0; rt < WR; ++rt)
#pragma unroll
        for (int ct = 0; ct < WC; ++ct) acc[rt][ct] = (f32x4){0.f, 0.f, 0.f, 0.f};

    const unsigned short* pa_hi = Ahi + (size_t)(row0 + r16) * K + kg * 8;
    const unsigned short* pa_lo = Alo + (size_t)(row0 + r16) * K + kg * 8;
    const unsigned short* pb_hi = Bhi + (size_t)lane * 8;
    const unsigned short* pb_lo = Blo + (size_t)lane * 8;

#pragma unroll
    for (int kt = 0; kt < KT; ++kt) {
        bf16x8 ah[WR], al[WR];
#pragma unroll
        for (int rt = 0; rt < WR; ++rt) {
            ah[rt] = *reinterpret_cast<const bf16x8*>(pa_hi + (size_t)rt * 16 * K + kt * 32);
            al[rt] = *reinterpret_cast<const bf16x8*>(pa_lo + (size_t)rt * 16 * K + kt * 32);
        }
#pragma unroll
        for (int ct = 0; ct < WC; ++ct) {
            const int nt = ct0 + ct;
            bf16x8 bh = *reinterpret_cast<const bf16x8*>(pb_hi + (size_t)(kt * NTall + nt) * 512);
            bf16x8 bl = *reinterpret_cast<const bf16x8*>(pb_lo + (size_t)(kt * NTall + nt) * 512);
#pragma unroll
            for (int rt = 0; rt < WR; ++rt) {
                acc[rt][ct] = __builtin_amdgcn_mfma_f32_16x16x32_bf16(ah[rt], bh, acc[rt][ct], 0, 0, 0);
                acc[rt][ct] = __builtin_amdgcn_mfma_f32_16x16x32_bf16(ah[rt], bl, acc[rt][ct], 0, 0, 0);
                acc[rt][ct] = __builtin_amdgcn_mfma_f32_16x16x32_bf16(al[rt], bh, acc[rt][ct], 0, 0, 0);
            }
        }
    }

    // C/D layout: col = lane&15, row = (lane>>4)*4 + i
    const int ccol = lane & 15;
#pragma unroll
    for (int rt = 0; rt < WR; ++rt) {
        const int crow0 = row0 + rt * 16 + (lane >> 4) * 4;
#pragma unroll
        for (int ct = 0; ct < WC; ++ct) {
            int col = (ct0 + ct) * 16 + ccol;
            float bv = BIAS ? bias[col] : 0.f;
#pragma unroll
            for (int i = 0; i < 4; ++i) {
                float v = acc[rt][ct][i] + bv;
                if (RELU) v = fmaxf(v, 0.f);
                if (PRESCALE) v *= dscale[crow0 + i];
                size_t idx = (size_t)(crow0 + i) * N + col;
                if (SPLITOUT) {
                    unsigned short h = f2bf(v);
                    Chi[idx] = h;
                    Clo[idx] = f2bf(v - bf2f(h));
                } else {
                    Cf[idx] = v;
                }
            }
        }
    }
}

extern "C" void kernel_launch(void* const* d_in, const int* in_sizes, int n_in,
                              void* d_out, int out_size, void* d_ws, size_t ws_size,
                              hipStream_t stream) {
    const float* x  = (const float*)d_in[0];
    const int*   ei = (const int*)d_in[1];
    const float* W1 = (const float*)d_in[2];
    const float* b1 = (const float*)d_in[3];
    const float* W2 = (const float*)d_in[4];
    const float* b2 = (const float*)d_in[5];
    float* out = (float*)d_out;

    const int* src = ei;
    const int* dst = ei + NE;

    // workspace layout (all offsets 256-aligned):
    char* ws = (char*)d_ws;
    int*   deg     = (int*)ws;                               // 200 KB
    int*   cursor  = (int*)(ws + 262144);
    int*   row_ptr = (int*)(ws + 524288);
    float* dinv    = (float*)(ws + 786432);                  // 256 KB slot (NPAD-safe)
    int*   csr_src = (int*)(ws + 1048576);                   // 2.56 MB
    int*   blk_sum = (int*)(ws + 3670016);
    int*   blk_off = (int*)(ws + 3674112);
    unsigned short* W1hi = (unsigned short*)(ws + 3678208);  // 64 KB each
    unsigned short* W1lo = (unsigned short*)(ws + 3743744);
    unsigned short* W2hi = (unsigned short*)(ws + 3809280);
    unsigned short* W2lo = (unsigned short*)(ws + 3874816);
    unsigned short* A1hi = (unsigned short*)(ws + 4194304);  // NPAD*128*2 = 12.81 MB
    unsigned short* A1lo = (unsigned short*)(ws + 17006592); // 12.81 MB
    unsigned short* H1hi = (unsigned short*)(ws + 29818880); // NPAD*256*2 = 25.62 MB
    unsigned short* H1lo = (unsigned short*)(ws + 55443456); // 25.62 MB
    float* H2 = (float*)(ws + 4194304);  // aliases A1hi+A1lo (dead by then)

    constexpr int BT = 256;
    const int gN = (NN + BT - 1) / BT;   // 196
    const int gE = (NE + BT - 1) / BT;   // 2500
    const int gG = (NN + 15) / 16;       // 3125 (16 nodes/block)
    constexpr int NRB = NPAD / 64;       // 782

    // CSR build
    k_zero_deg<<<gN, BT, 0, stream>>>(deg);
    k_count_deg<<<gE, BT, 0, stream>>>(dst, deg);
    k_dinv<<<gN, BT, 0, stream>>>(deg, dinv);
    k_scan_blk<<<NCHUNK, SCB, 0, stream>>>(deg, row_ptr, blk_sum);
    k_scan_top<<<1, SCB, 0, stream>>>(blk_sum, blk_off);
    k_scan_add<<<NCHUNK, SCB, 0, stream>>>(row_ptr, blk_off, cursor);
    k_fill_csr<<<gE, BT, 0, stream>>>(src, dst, row_ptr, cursor, csr_src);

    // W packs (tiny)
    k_wpack<F_IN, F_HID><<<16, BT, 0, stream>>>(W1, W1hi, W1lo);
    k_wpack<F_HID, F_OUT><<<16, BT, 0, stream>>>(W2, W2hi, W2lo);

    // layer 1: agg1 = Ahat @ x  (split bf16 out; per-edge dinv)
    k_gather<false, true, false><<<gG, BT, 0, stream>>>(x, csr_src, row_ptr, dinv,
                                                        nullptr, nullptr, A1hi, A1lo);
    // H1 = relu(agg1 @ W1 + b1)  (split bf16 out)
    k_gemm_mfma<F_IN, F_HID, true, true, true, false><<<NRB * 2, 64, 0, stream>>>(
        A1hi, A1lo, W1hi, W1lo, b1, nullptr, H1hi, H1lo, nullptr);
    // Hs2 = dinv * (H1 @ W2)  (f32, prescaled for gather-2; aliases dead A1)
    k_gemm_mfma<F_HID, F_OUT, false, false, false, true><<<NRB, 64, 0, stream>>>(
        H1hi, H1lo, W2hi, W2lo, nullptr, dinv, nullptr, nullptr, H2);
    // out = dinv[v]*(Hs2[v] + sum Hs2[s]) + b2
    k_gather<true, false, true><<<gG, BT, 0, stream>>>(H2, csr_src, row_ptr, dinv,
                                                       b2, out, nullptr, nullptr);
}